// Round 11
// baseline (33.763 us; speedup 1.0000x reference)
//
#include <hip/hip_runtime.h>

typedef __bf16 bf16x8 __attribute__((ext_vector_type(8)));
typedef float  f32x16 __attribute__((ext_vector_type(16)));

#define NN 512
#define TT 32
#define HH 8
#define CCH 128
#define RS (TT*CCH)          // 4096 floats per node row
#define WS_U4_PER_TH 2048    // 32KB per (t,h): [k2f 1024 uint4][vpfc 1024 uint4]
#define WS_OUT_OFF 524288    // uint4 offset of packed attn-output region (8.4MB)

__device__ __forceinline__ unsigned cvt_pk_bf16(float a, float b) {
    unsigned r;
    asm("v_cvt_pk_bf16_f32 %0, %1, %2" : "=v"(r) : "v"(a), "v"(b));
    return r;
}

// swap(a,b): a <- [a.lo | b.lo], b <- [a.hi | b.hi]  (lanes 0-31 / 32-63)
__device__ __forceinline__ void permswap(unsigned& a, unsigned& b) {
    asm volatile("v_permlane32_swap_b32 %0, %1" : "+v"(a), "+v"(b));
}

// hi/lo bf16 split of 8 consecutive floats.
__device__ __forceinline__ void split8(const float4 a, const float4 b, uint4& h, uint4& l) {
    const unsigned ax = __float_as_uint(a.x), ay = __float_as_uint(a.y);
    const unsigned az = __float_as_uint(a.z), aw = __float_as_uint(a.w);
    const unsigned bx = __float_as_uint(b.x), by = __float_as_uint(b.y);
    const unsigned bz = __float_as_uint(b.z), bw = __float_as_uint(b.w);
    h.x = (ay & 0xFFFF0000u) | (ax >> 16);
    h.y = (aw & 0xFFFF0000u) | (az >> 16);
    h.z = (by & 0xFFFF0000u) | (bx >> 16);
    h.w = (bw & 0xFFFF0000u) | (bz >> 16);
    const float lax = a.x - __uint_as_float(ax & 0xFFFF0000u);
    const float lay = a.y - __uint_as_float(ay & 0xFFFF0000u);
    const float laz = a.z - __uint_as_float(az & 0xFFFF0000u);
    const float law = a.w - __uint_as_float(aw & 0xFFFF0000u);
    const float lbx = b.x - __uint_as_float(bx & 0xFFFF0000u);
    const float lby = b.y - __uint_as_float(by & 0xFFFF0000u);
    const float lbz = b.z - __uint_as_float(bz & 0xFFFF0000u);
    const float lbw = b.w - __uint_as_float(bw & 0xFFFF0000u);
    l.x = cvt_pk_bf16(lax, lay);
    l.y = cvt_pk_bf16(laz, law);
    l.z = cvt_pk_bf16(lbx, lby);
    l.w = cvt_pk_bf16(lbz, lbw);
}

// ---------------------------------------------------------------------------
// proj (R8-validated verbatim): grid 512 = (t, node-group g of 32), 512 threads.
__global__ __launch_bounds__(512) void proj_kernel(
    const float* __restrict__ vals,
    const float* __restrict__ keys,
    const float* __restrict__ Wq,
    const float* __restrict__ Wk,
    const float* __restrict__ Wv,
    uint4* __restrict__ ws)
{
    __shared__ float wlds[512];       // 2KB   M (scaled) + Wv
    __shared__ float stage[32*164];   // 21KB  staged input slice (keys, then vals)
    __shared__ uint4 k2l[512];        // 8KB   K2 frags for this (t,g), all 8 h
    __shared__ uint4 vpl[512];        // 8KB   Vp frags for this (t,g), all 8 h

    const int tid = threadIdx.x;
    const int bid = blockIdx.x;
    const int t = bid >> 4;
    const int g = bid & 15;

    // Phase A: M[d][dp] = sum_e Wq[e][d]*Wk[e][dp], scaled by (1/sqrt(128))*log2(e)
    if (tid < 256) {
        const int d = tid >> 4, dp = tid & 15;
        float a = 0.f;
        #pragma unroll
        for (int e = 0; e < 16; ++e) a = fmaf(Wq[e*16+d], Wk[e*16+dp], a);
        wlds[tid]       = a * 0.12751744503131863f;
        wlds[256 + tid] = Wv[tid];
    }
    // Stage keys slice (coalesced)
    #pragma unroll
    for (int i = 0; i < 2; ++i) {
        const int idx = i*512 + tid;          // row*32 + c4
        const int row = idx >> 5, c4 = idx & 31;
        const float4 v = *(const float4*)(keys + (size_t)(g*32+row)*RS + (size_t)t*CCH + c4*4);
        *(float4*)&stage[row*164 + (c4>>2)*20 + (c4&3)*4] = v;
    }
    __syncthreads();

    const int u = tid & 255, dhalf = tid >> 8;
    const int r = u >> 3, h = u & 7;

    // K2 compute: 8 d's per thread
    {
        float kr[16];
        #pragma unroll
        for (int i = 0; i < 16; i += 4)
            *(float4*)&kr[i] = *(const float4*)&stage[r*164 + h*20 + i];
        float k2[8];
        #pragma unroll
        for (int dd = 0; dd < 8; ++dd) {
            const int d = dhalf*8 + dd;
            const float4 m0 = *(const float4*)&wlds[d*16];
            const float4 m1 = *(const float4*)&wlds[d*16+4];
            const float4 m2 = *(const float4*)&wlds[d*16+8];
            const float4 m3 = *(const float4*)&wlds[d*16+12];
            k2[dd] = kr[0]*m0.x + kr[1]*m0.y + kr[2]*m0.z + kr[3]*m0.w
                   + kr[4]*m1.x + kr[5]*m1.y + kr[6]*m1.z + kr[7]*m1.w
                   + kr[8]*m2.x + kr[9]*m2.y + kr[10]*m2.z + kr[11]*m2.w
                   + kr[12]*m3.x + kr[13]*m3.y + kr[14]*m3.z + kr[15]*m3.w;
        }
        uint4 p;
        p.x = cvt_pk_bf16(k2[0],k2[1]);  p.y = cvt_pk_bf16(k2[2],k2[3]);
        p.z = cvt_pk_bf16(k2[4],k2[5]);  p.w = cvt_pk_bf16(k2[6],k2[7]);
        k2l[h*64 + dhalf*32 + r] = p;
    }
    __syncthreads();

    // Stage vals slice
    #pragma unroll
    for (int i = 0; i < 2; ++i) {
        const int idx = i*512 + tid;
        const int row = idx >> 5, c4 = idx & 31;
        const float4 v = *(const float4*)(vals + (size_t)(g*32+row)*RS + (size_t)t*CCH + c4*4);
        *(float4*)&stage[row*164 + (c4>>2)*20 + (c4&3)*4] = v;
    }
    __syncthreads();

    // Vp compute: 8 e's per thread
    {
        float vr[16];
        #pragma unroll
        for (int i = 0; i < 16; i += 4)
            *(float4*)&vr[i] = *(const float4*)&stage[r*164 + h*20 + i];
        float vp[8];
        #pragma unroll
        for (int dd = 0; dd < 8; ++dd) {
            const int d = dhalf*8 + dd;
            const float4 w0 = *(const float4*)&wlds[256 + d*16];
            const float4 w1 = *(const float4*)&wlds[256 + d*16+4];
            const float4 w2 = *(const float4*)&wlds[256 + d*16+8];
            const float4 w3 = *(const float4*)&wlds[256 + d*16+12];
            vp[dd] = vr[0]*w0.x + vr[1]*w0.y + vr[2]*w0.z + vr[3]*w0.w
                   + vr[4]*w1.x + vr[5]*w1.y + vr[6]*w1.z + vr[7]*w1.w
                   + vr[8]*w2.x + vr[9]*w2.y + vr[10]*w2.z + vr[11]*w2.w
                   + vr[12]*w3.x + vr[13]*w3.y + vr[14]*w3.z + vr[15]*w3.w;
        }
        unsigned short* vph = (unsigned short*)vpl;
        const int f_loc = r >> 4;
        const int lg = (r >> 3) & 1;
        const int ii = r & 7;
        #pragma unroll
        for (int dd = 0; dd < 8; ++dd) {
            const int e = dhalf*8 + dd;
            vph[(size_t)(h*64 + f_loc*32 + lg*16 + e)*8 + ii] =
                (unsigned short)(cvt_pk_bf16(vp[dd], vp[dd]) & 0xffffu);
        }
    }
    __syncthreads();

    // Copy out frag tiles (1KB contiguous per h per region)
    {
        const int hh = tid >> 6, e = tid & 63;
        uint4* dst = ws + (size_t)(t*8 + hh)*WS_U4_PER_TH;
        dst[g*64 + e]        = k2l[tid];
        dst[1024 + g*64 + e] = vpl[tid];
    }
}

// ---------------------------------------------------------------------------
// attn (R8-validated structure: grid 1024, 256 thr, 4 waves, jj=1; th=bid&255,
// qq=bid>>8 so a th's 4 blocks share an XCD -> frag re-stages are L2 hits).
// ONLY change vs R8: epilogue writes PACKED obuf[th][nq][16] (fully coalesced,
// block-private region, no cross-XCD partial-line RMW).
__global__ __launch_bounds__(256, 4) void attn_mfma(
    const float* __restrict__ vals,
    const uint4* __restrict__ ws,
    float* __restrict__ obuf)
{
    __shared__ uint4 k2f[1024];    // 16KB
    __shared__ uint4 vpfc[1024];   // 16KB (e-rows 0..15 only)
    __shared__ uint4 dummy[32];    // pad rows: e16=ones, e17..31=0

    const int tid  = threadIdx.x;
    const int lane = tid & 63;
    const int wv   = tid >> 6;
    const int bid  = blockIdx.x;
    const int th   = bid & 255;
    const int qq   = bid >> 8;
    const int t = th >> 3;
    const int h = th & 7;
    const size_t cb0 = (size_t)t*CCH + h*16;

    const int qr = lane & 31;
    const int dh = (lane >> 5) * 8;

    // Early Q loads (raw `values` rows — the preserved source bug)
    const int nq = qq*128 + wv*32 + qr;
    const float* qp = vals + (size_t)nq*RS + cb0 + dh;
    const float4 qa = *(const float4*)qp;
    const float4 qb = *(const float4*)(qp + 4);

    // Stage fragments from ws (coalesced uint4 copy)
    const uint4* src = ws + (size_t)th*WS_U4_PER_TH;
    #pragma unroll
    for (int i = 0; i < 4; ++i) k2f[i*256 + tid]  = src[i*256 + tid];
    #pragma unroll
    for (int i = 0; i < 4; ++i) vpfc[i*256 + tid] = src[1024 + i*256 + tid];
    if (tid < 32) {
        const unsigned pv = (tid == 0 || tid == 16) ? 0x3F803F80u : 0u;
        dummy[tid] = make_uint4(pv, pv, pv, pv);
    }
    __syncthreads();

    // Q B-frag
    bf16x8 qf;
    {
        uint4 u;
        u.x = cvt_pk_bf16(qa.x, qa.y);
        u.y = cvt_pk_bf16(qa.z, qa.w);
        u.z = cvt_pk_bf16(qb.x, qb.y);
        u.w = cvt_pk_bf16(qb.z, qb.w);
        qf = __builtin_bit_cast(bf16x8, u);
    }

    // Per-lane Vp source: live lanes walk vpfc, pad lanes pin to dummy
    const bool vlive = (lane & 31) < 16;
    const uint4* vbase = vlive ? (vpfc + (lane & 31) + (lane >> 5)*16)
                               : (dummy + ((lane & 31) - 16) + (lane >> 5)*16);
    const int kstep = vlive ? 64 : 0;
    const int sstep = vlive ? 32 : 0;

    f32x16 zc, acc;
    #pragma unroll
    for (int r2 = 0; r2 < 16; ++r2) { zc[r2] = 0.f; acc[r2] = 0.f; }

    #pragma unroll 2
    for (int kt = 0; kt < 16; ++kt) {
        const bf16x8 ak = __builtin_bit_cast(bf16x8, k2f[kt*64 + lane]);
        const uint4 rd0 = vbase[kt*kstep];
        const uint4 rd1 = vbase[kt*kstep + sstep];

        const f32x16 s = __builtin_amdgcn_mfma_f32_32x32x16_bf16(ak, qf, zc, 0, 0, 0);
        unsigned w0 = cvt_pk_bf16(__builtin_amdgcn_exp2f(s[0]),  __builtin_amdgcn_exp2f(s[1]));
        unsigned w1 = cvt_pk_bf16(__builtin_amdgcn_exp2f(s[2]),  __builtin_amdgcn_exp2f(s[3]));
        unsigned w2 = cvt_pk_bf16(__builtin_amdgcn_exp2f(s[4]),  __builtin_amdgcn_exp2f(s[5]));
        unsigned w3 = cvt_pk_bf16(__builtin_amdgcn_exp2f(s[6]),  __builtin_amdgcn_exp2f(s[7]));
        unsigned w4 = cvt_pk_bf16(__builtin_amdgcn_exp2f(s[8]),  __builtin_amdgcn_exp2f(s[9]));
        unsigned w5 = cvt_pk_bf16(__builtin_amdgcn_exp2f(s[10]), __builtin_amdgcn_exp2f(s[11]));
        unsigned w6 = cvt_pk_bf16(__builtin_amdgcn_exp2f(s[12]), __builtin_amdgcn_exp2f(s[13]));
        unsigned w7 = cvt_pk_bf16(__builtin_amdgcn_exp2f(s[14]), __builtin_amdgcn_exp2f(s[15]));
        permswap(w0, w2);
        permswap(w1, w3);
        permswap(w4, w6);
        permswap(w5, w7);
        const uint4 pb0 = make_uint4(w0, w1, w2, w3);
        const uint4 pb1 = make_uint4(w4, w5, w6, w7);
        acc = __builtin_amdgcn_mfma_f32_32x32x16_bf16(
                  __builtin_bit_cast(bf16x8, rd0), __builtin_bit_cast(bf16x8, pb0), acc, 0, 0, 0);
        acc = __builtin_amdgcn_mfma_f32_32x32x16_bf16(
                  __builtin_bit_cast(bf16x8, rd1), __builtin_bit_cast(bf16x8, pb1), acc, 0, 0, 0);
    }

    // Epilogue (validated reg->e map). PACKED output: obuf[th][nq][16].
    const bool lohalf = lane < 32;
    float den = acc[8];
    const float ds = __shfl_xor(den, 32);
    if (!lohalf) den = ds;
    const float inv = 1.f / den;
    float* orow = obuf + ((size_t)th*512 + nq)*16 + (lohalf ? 0 : 4);
    float4 o0, o1;
    o0.x = acc[0]*inv; o0.y = acc[1]*inv; o0.z = acc[2]*inv; o0.w = acc[3]*inv;
    o1.x = acc[4]*inv; o1.y = acc[5]*inv; o1.z = acc[6]*inv; o1.w = acc[7]*inv;
    *(float4*)orow       = o0;
    *(float4*)(orow + 8) = o1;
}

// ---------------------------------------------------------------------------
// fc (R8-validated math): out = X @ Wfc^T + b -> d_out. ONLY change vs R8:
// X gathered from the packed attn output (xin[th][n][16]); 8 consecutive
// lanes read one contiguous 128B line (n, n+1 of one th — both consumed by
// this block).
__global__ __launch_bounds__(512) void fc_mfma(
    const float* __restrict__ xin,
    float* __restrict__ out,
    const float* __restrict__ Wfc,
    const float* __restrict__ bfc)
{
    __shared__ float xs[64 * 132];    // 33.8KB fp32 X tile, pad 132
    __shared__ uint4 whf[2048];       // 32KB  W-hi A-frags [ct][ks][lane]
    __shared__ uint4 wlf[2048];       // 32KB  W-lo A-frags

    const int tid  = threadIdx.x;
    const int lane = tid & 63;
    const int wv   = tid >> 6;
    const int rowbase = blockIdx.x * 64;
    const int n0 = blockIdx.x * 2;    // rows rowbase..+63 = nodes {n0, n0+1} x t 0..31

    // Stage X from packed layout: idx = th*8 + nn*4 + e4
    #pragma unroll
    for (int i = 0; i < 4; ++i) {
        const int idx = i*512 + tid;          // 0..2047
        const int e4 = idx & 3;
        const int nn = (idx >> 2) & 1;
        const int th = idx >> 3;              // 0..255
        const int t  = th >> 3, h = th & 7;
        const float4 v = *(const float4*)(xin + ((size_t)th*512 + n0 + nn)*16 + e4*4);
        *(float4*)&xs[(nn*32 + t)*132 + h*16 + e4*4] = v;
    }
    // Stage W fragments (hi/lo split)
    #pragma unroll
    for (int i = 0; i < 4; ++i) {
        const int idx = i*512 + tid;          // 0..2047
        const int ct = idx >> 9, ks = (idx >> 6) & 7, l = idx & 63;
        const int e = ct*32 + (l & 31);
        const int k = ks*16 + (l >> 5)*8;
        const float* wp = Wfc + (size_t)e*CCH + k;
        const float4 wa = *(const float4*)wp;
        const float4 wb = *(const float4*)(wp + 4);
        uint4 hh, lo;
        split8(wa, wb, hh, lo);
        whf[idx] = hh;
        wlf[idx] = lo;
    }
    __syncthreads();

    const int rt = wv >> 2;
    const int ct = wv & 3;
    const int xrow = rt*32 + (lane & 31);
    const int kof  = (lane >> 5) * 8;

    f32x16 acc;
    #pragma unroll
    for (int r2 = 0; r2 < 16; ++r2) acc[r2] = 0.f;

    #pragma unroll 2
    for (int ks = 0; ks < 8; ++ks) {
        const float* xp = &xs[xrow*132 + ks*16 + kof];
        const float4 xa = *(const float4*)xp;
        const float4 xb = *(const float4*)(xp + 4);
        uint4 bh, bl;
        split8(xa, xb, bh, bl);
        const bf16x8 Bh = __builtin_bit_cast(bf16x8, bh);
        const bf16x8 Bl = __builtin_bit_cast(bf16x8, bl);
        const int base = ct*512 + ks*64 + lane;
        const bf16x8 Ah = __builtin_bit_cast(bf16x8, whf[base]);
        const bf16x8 Al = __builtin_bit_cast(bf16x8, wlf[base]);
        acc = __builtin_amdgcn_mfma_f32_32x32x16_bf16(Ah, Bh, acc, 0, 0, 0);
        acc = __builtin_amdgcn_mfma_f32_32x32x16_bf16(Al, Bh, acc, 0, 0, 0);
        acc = __builtin_amdgcn_mfma_f32_32x32x16_bf16(Ah, Bl, acc, 0, 0, 0);
    }

    const int orow = rowbase + rt*32 + (lane & 31);
    const int hio  = (lane >> 5) * 4;
    #pragma unroll
    for (int g = 0; g < 4; ++g) {
        const int e0 = ct*32 + g*8 + hio;
        const float4 b = *(const float4*)&bfc[e0];
        float4 o;
        o.x = acc[g*4+0] + b.x;
        o.y = acc[g*4+1] + b.y;
        o.z = acc[g*4+2] + b.z;
        o.w = acc[g*4+3] + b.w;
        *(float4*)&out[(size_t)orow*CCH + e0] = o;
    }
}

extern "C" void kernel_launch(void* const* d_in, const int* in_sizes, int n_in,
                              void* d_out, int out_size, void* d_ws, size_t ws_size,
                              hipStream_t stream)
{
    const float* vals = (const float*)d_in[0];
    const float* keys = (const float*)d_in[1];
    // d_in[2] = query (unused — reference builds q from `values`)
    // d_in[3] = heads (fixed 8)
    const float* Wq  = (const float*)d_in[4];
    const float* Wk  = (const float*)d_in[5];
    const float* Wv  = (const float*)d_in[6];
    const float* Wfc = (const float*)d_in[7];
    const float* bfc = (const float*)d_in[8];
    float* out = (float*)d_out;
    uint4* ws = (uint4*)d_ws;                      // frags 8MB | packed attn-out 8.4MB
    float* wsout = (float*)(ws + WS_OUT_OFF);      // packed [th][nq][16]

    proj_kernel<<<dim3(512),  dim3(512), 0, stream>>>(vals, keys, Wq, Wk, Wv, ws);
    attn_mfma  <<<dim3(1024), dim3(256), 0, stream>>>(vals, ws, wsout);
    fc_mfma    <<<dim3(256),  dim3(512), 0, stream>>>(wsout, out, Wfc, bfc);
}